// Round 7
// baseline (800.353 us; speedup 1.0000x reference)
//
#include <hip/hip_runtime.h>

#define N_NODES 10000
#define N_EDGES 640000
#define NODE_DIM 64
#define HIDDEN 128
#define NUM_LAYERS 4
#define NT (N_EDGES + N_NODES)   // 650000 edge slots incl. self loops
#define EB7 32                   // edge slots per block in k_edge7

typedef __attribute__((ext_vector_type(8))) short short8v;
typedef __attribute__((ext_vector_type(16))) float f32x16;

// ---------------- edge dtype detection / normalization ----------------
__global__ void k_detect(const int* __restrict__ ei, int* __restrict__ flag)
{
    __shared__ int nz;
    if (threadIdx.x == 0) nz = 0;
    __syncthreads();
    int found = 0;
    for (int k = threadIdx.x; k < 2048; k += 256) {
        int pos = 2 * (k * 156) + 1;
        if (ei[pos] != 0) found = 1;
    }
    if (found) atomicOr(&nz, 1);
    __syncthreads();
    if (threadIdx.x == 0) flag[0] = nz;          // 1 = int32 layout, 0 = int64
}

__global__ void k_normalize(const int* __restrict__ ei, const int* __restrict__ flag,
                            int* __restrict__ srcN, int* __restrict__ dstN)
{
    int e = blockIdx.x * 256 + threadIdx.x;
    if (e >= N_EDGES) return;
    if (flag[0]) {
        srcN[e] = ei[e];
        dstN[e] = ei[N_EDGES + e];
    } else {
        srcN[e] = ei[2 * e];
        dstN[e] = ei[2 * (N_EDGES + e)];
    }
}

__global__ void k_zero(int* __restrict__ p, int n)
{
    int i = blockIdx.x * 256 + threadIdx.x;
    if (i < n) p[i] = 0;
}

__global__ void k_count(const int* __restrict__ dstN, int* __restrict__ cnt)
{
    int e = blockIdx.x * 256 + threadIdx.x;
    if (e < N_EDGES) atomicAdd(&cnt[dstN[e]], 1);
}

__global__ void k_scan(const int* __restrict__ cnt, int* __restrict__ cursor)
{
    __shared__ int part[256];
    const int t = threadIdx.x;
    const int CH = (N_NODES + 255) / 256;        // 40
    int lo = t * CH, hi = min(N_NODES, lo + CH);
    int s = 0;
    for (int i = lo; i < hi; ++i) s += cnt[i] + 1;
    part[t] = s;
    __syncthreads();
    for (int off = 1; off < 256; off <<= 1) {
        int v = (t >= off) ? part[t - off] : 0;
        __syncthreads();
        part[t] += v;
        __syncthreads();
    }
    int base = (t == 0) ? 0 : part[t - 1];
    for (int i = lo; i < hi; ++i) {
        cursor[i] = base;
        base += cnt[i] + 1;
    }
}

__global__ void k_scatter(const int* __restrict__ srcN, const int* __restrict__ dstN,
                          int* __restrict__ cursor,
                          int* __restrict__ esrc, int* __restrict__ edst)
{
    int e = blockIdx.x * 256 + threadIdx.x;
    if (e < N_EDGES) {
        int d = dstN[e];
        int pos = atomicAdd(&cursor[d], 1);
        esrc[pos] = srcN[e];
        edst[pos] = d;
    }
}

__global__ void k_selfloop(int* __restrict__ cursor,
                           int* __restrict__ esrc, int* __restrict__ edst)
{
    int n = blockIdx.x * 256 + threadIdx.x;
    if (n < N_NODES) {
        int pos = atomicAdd(&cursor[n], 1);
        esrc[pos] = n;
        edst[pos] = n;
    }
}

// Wa = W1[:,:128,:] - W1[:,128:,:] (x_i side);  Wb = W1[:,128:,:] (x_j side)
__global__ void k_prepw(const float* __restrict__ W1, float* __restrict__ Wa,
                        float* __restrict__ Wb)
{
    int i = blockIdx.x * 256 + threadIdx.x;      // over L*128*128
    if (i >= NUM_LAYERS * 128 * 128) return;
    int l = i >> 14, rem = i & 16383;
    float top = W1[l * 32768 + rem];
    float bot = W1[l * 32768 + 16384 + rem];
    Wa[i] = top - bot;
    Wb[i] = bot;
}

__device__ __forceinline__ unsigned short bf16rne(float f)
{
    unsigned int u = __float_as_uint(f);
    unsigned int r = u + 0x7FFFu + ((u >> 16) & 1u);
    return (unsigned short)(r >> 16);
}

// W2 -> fragment-linear hi/lo bf16, lane-contiguous:
// W2f[l][c][tile][p][lane][j]  (lane = kh*32+m holds W2[k=16c+8kh+j][n=32tile+m])
__global__ void k_prepw2(const float* __restrict__ W2, short* __restrict__ W2f)
{
    int i = blockIdx.x * 256 + threadIdx.x;      // over L*128*128
    if (i >= NUM_LAYERS * 128 * 128) return;
    int l = i >> 14, rem = i & 16383;            // rem = k*128 + n
    int k = rem >> 7, n = rem & 127;
    float w = W2[i];
    unsigned short hs = bf16rne(w);
    float hf = __uint_as_float((unsigned int)hs << 16);
    unsigned short ls = bf16rne(w - hf);
    int c = k >> 4, kh = (k >> 3) & 1, j = k & 7;
    int tile = n >> 5, m = n & 31;
    int lane = kh * 32 + m;
    size_t base = (size_t)l * 32768 + c * 4096 + tile * 1024 + lane * 8 + j;
    W2f[base]       = (short)hs;
    W2f[base + 512] = (short)ls;
}

__device__ __forceinline__ unsigned int encf(float f)
{
    unsigned int b = __float_as_uint(f);
    return b ^ ((unsigned int)((int)b >> 31) | 0x80000000u);
}

__device__ __forceinline__ float decenc(unsigned int u)
{
    unsigned int bits = (u & 0x80000000u) ? (u ^ 0x80000000u) : ~u;
    return __uint_as_float(bits);
}

// relu(a+b) for float4
__device__ __forceinline__ float4 radd4(float4 a, float4 b)
{
    return make_float4(fmaxf(a.x + b.x, 0.f), fmaxf(a.y + b.y, 0.f),
                       fmaxf(a.z + b.z, 0.f), fmaxf(a.w + b.w, 0.f));
}

// split 8 non-negative floats into bf16 hi (trunc) + lo (RNE of residual),
// packed as uint4 words (elem j low-to-high)
__device__ __forceinline__ void split8(float4 x0, float4 x1, uint4& H, uint4& L)
{
    float f[8] = {x0.x, x0.y, x0.z, x0.w, x1.x, x1.y, x1.z, x1.w};
    unsigned int h[4], l[4];
#pragma unroll
    for (int w = 0; w < 4; ++w) {
        unsigned int ua = __float_as_uint(f[2 * w]);
        unsigned int ub = __float_as_uint(f[2 * w + 1]);
        h[w] = (ub & 0xFFFF0000u) | (ua >> 16);
        float ra = f[2 * w]     - __uint_as_float(ua & 0xFFFF0000u);
        float rb = f[2 * w + 1] - __uint_as_float(ub & 0xFFFF0000u);
        unsigned int va = __float_as_uint(ra);
        unsigned int vb = __float_as_uint(rb);
        va = va + 0x7FFFu + ((va >> 16) & 1u);
        vb = vb + 0x7FFFu + ((vb >> 16) & 1u);
        l[w] = (va >> 16) | (vb & 0xFFFF0000u);
    }
    H = make_uint4(h[0], h[1], h[2], h[3]);
    L = make_uint4(l[0], l[1], l[2], l[3]);
}

// ---------------- node GEMM, 32-row tiles, optional enc-decode + dual output --------
// X = (enc ? decode(enc)+bprev : Xf); CA = X@WA + biasA; if HASB: CB = X@WB.
// enc rows are re-zeroed after decode (ready for this layer's edge atomics).
template <int K, bool HASB>
__global__ __launch_bounds__(256) void k_gemm32(
    const float* __restrict__ Xf, unsigned int* __restrict__ enc,
    const float* __restrict__ bprev,
    const float* __restrict__ WA, const float* __restrict__ WB,
    const float* __restrict__ biasA,
    float* __restrict__ CA, float* __restrict__ CB, int M)
{
    constexpr int LDX = K + 4;
    __shared__ float Xs[32 * LDX];
    const int t = threadIdx.x;
    const int row0 = blockIdx.x * 32;
    constexpr int F4R = K / 4;
    if (enc) {
        for (int i = t; i < 32 * F4R; i += 256) {
            int r = i / F4R, f = i % F4R;
            int gr = row0 + r;
            float4 v = make_float4(0.f, 0.f, 0.f, 0.f);
            if (gr < M) {
                uint4 u = *(const uint4*)(enc + (size_t)gr * K + 4 * f);
                v.x = decenc(u.x) + bprev[4 * f + 0];
                v.y = decenc(u.y) + bprev[4 * f + 1];
                v.z = decenc(u.z) + bprev[4 * f + 2];
                v.w = decenc(u.w) + bprev[4 * f + 3];
                uint4 z = make_uint4(0u, 0u, 0u, 0u);
                *(uint4*)(enc + (size_t)gr * K + 4 * f) = z;
            }
            *(float4*)(Xs + r * LDX + 4 * f) = v;
        }
    } else {
        for (int i = t; i < 32 * F4R; i += 256) {
            int r = i / F4R, f = i % F4R;
            int gr = row0 + r;
            float4 v = make_float4(0.f, 0.f, 0.f, 0.f);
            if (gr < M) v = *(const float4*)(Xf + (size_t)gr * K + 4 * f);
            *(float4*)(Xs + r * LDX + 4 * f) = v;
        }
    }
    __syncthreads();

    const int rg = t >> 4, cg = t & 15;      // rows rg*2..+1, cols cg*8..+7
    float accA[2][8], accB[2][8];
#pragma unroll
    for (int i = 0; i < 2; ++i)
#pragma unroll
        for (int j = 0; j < 8; ++j) { accA[i][j] = 0.f; accB[i][j] = 0.f; }

#pragma unroll 4
    for (int k = 0; k < K; ++k) {
        float4 wa0 = *(const float4*)(WA + k * 128 + cg * 8);
        float4 wa1 = *(const float4*)(WA + k * 128 + cg * 8 + 4);
        float x0 = Xs[(rg * 2) * LDX + k];
        float x1 = Xs[(rg * 2 + 1) * LDX + k];
        accA[0][0] += x0 * wa0.x; accA[0][1] += x0 * wa0.y;
        accA[0][2] += x0 * wa0.z; accA[0][3] += x0 * wa0.w;
        accA[0][4] += x0 * wa1.x; accA[0][5] += x0 * wa1.y;
        accA[0][6] += x0 * wa1.z; accA[0][7] += x0 * wa1.w;
        accA[1][0] += x1 * wa0.x; accA[1][1] += x1 * wa0.y;
        accA[1][2] += x1 * wa0.z; accA[1][3] += x1 * wa0.w;
        accA[1][4] += x1 * wa1.x; accA[1][5] += x1 * wa1.y;
        accA[1][6] += x1 * wa1.z; accA[1][7] += x1 * wa1.w;
        if constexpr (HASB) {
            float4 wb0 = *(const float4*)(WB + k * 128 + cg * 8);
            float4 wb1 = *(const float4*)(WB + k * 128 + cg * 8 + 4);
            accB[0][0] += x0 * wb0.x; accB[0][1] += x0 * wb0.y;
            accB[0][2] += x0 * wb0.z; accB[0][3] += x0 * wb0.w;
            accB[0][4] += x0 * wb1.x; accB[0][5] += x0 * wb1.y;
            accB[0][6] += x0 * wb1.z; accB[0][7] += x0 * wb1.w;
            accB[1][0] += x1 * wb0.x; accB[1][1] += x1 * wb0.y;
            accB[1][2] += x1 * wb0.z; accB[1][3] += x1 * wb0.w;
            accB[1][4] += x1 * wb1.x; accB[1][5] += x1 * wb1.y;
            accB[1][6] += x1 * wb1.z; accB[1][7] += x1 * wb1.w;
        }
    }
    float4 b0 = *(const float4*)(biasA + cg * 8);
    float4 b1 = *(const float4*)(biasA + cg * 8 + 4);
#pragma unroll
    for (int i = 0; i < 2; ++i) {
        int r = row0 + rg * 2 + i;
        if (r < M) {
            *(float4*)(CA + (size_t)r * 128 + cg * 8) =
                make_float4(accA[i][0] + b0.x, accA[i][1] + b0.y,
                            accA[i][2] + b0.z, accA[i][3] + b0.w);
            *(float4*)(CA + (size_t)r * 128 + cg * 8 + 4) =
                make_float4(accA[i][4] + b1.x, accA[i][5] + b1.y,
                            accA[i][6] + b1.z, accA[i][7] + b1.w);
            if constexpr (HASB) {
                *(float4*)(CB + (size_t)r * 128 + cg * 8) =
                    make_float4(accB[i][0], accB[i][1], accB[i][2], accB[i][3]);
                *(float4*)(CB + (size_t)r * 128 + cg * 8 + 4) =
                    make_float4(accB[i][4], accB[i][5], accB[i][6], accB[i][7]);
            }
        }
    }
}

// ---------------- EdgeConv v7: EB=32, 8 blocks/CU, XCD swizzle ----------------
// LDS unit L = p*512 + c*64 + kh*32 + row, stored at phys = L ^ c (conflict-free
// writes: lane octet spans 8 chunks; reads: octet spans 8 groups).
// Staging: 8 threads/slot; thread c loads 64B contiguous of A and B (1 line each).
// k-loop: 3-term hi/lo MFMA, B streamed from global W2f, +1 chunk prefetch.
// Aggregation: block-uniform fast path (tree max + 1 atomic) else segment walk.
__global__ __launch_bounds__(256, 8) void k_edge7(
    const float* __restrict__ A, const float* __restrict__ Bm,
    const int* __restrict__ esrc, const int* __restrict__ edst,
    const short* __restrict__ W2l, unsigned int* __restrict__ enc)
{
    __shared__ __align__(16) short Ts[1024 * 8];   // 16 KB
    __shared__ int dsts[EB7];

    const int t = threadIdx.x;
    // bijective XCD-chunked block swizzle (m204 form)
    const int nwg = (int)gridDim.x;
    const int orig = (int)blockIdx.x;
    const int xcd = orig & 7, idx = orig >> 3;
    const int qq = nwg >> 3, rr = nwg & 7;
    const int bid = (xcd < rr ? xcd * (qq + 1) : rr * (qq + 1) + (xcd - rr) * qq) + idx;
    const int s0 = bid * EB7;

    // ---- stage: thread (row = t>>3, c = t&7) handles k in [16c, 16c+16) ----
    {
        const int row = t >> 3;
        const int c   = t & 7;
        const int slot = s0 + row;
        int dst = -1, src = 0;
        if (slot < NT) { dst = edst[slot]; src = esrc[slot]; }
        if (c == 0) dsts[row] = dst;

        const int u_h0 = ((c * 64 +      row) ^ c) * 8;         // p0 kh0
        const int u_h1 = ((c * 64 + 32 + row) ^ c) * 8;         // p0 kh1
        const int u_l0 = ((512 + c * 64 +      row) ^ c) * 8;   // p1 kh0
        const int u_l1 = ((512 + c * 64 + 32 + row) ^ c) * 8;   // p1 kh1

        if (dst >= 0) {
            const float* Ar = A  + (size_t)dst * HIDDEN + c * 16;
            const float* Br = Bm + (size_t)src * HIDDEN + c * 16;
            float4 a0 = *(const float4*)(Ar + 0);
            float4 a1 = *(const float4*)(Ar + 4);
            float4 a2 = *(const float4*)(Ar + 8);
            float4 a3 = *(const float4*)(Ar + 12);
            float4 c0 = *(const float4*)(Br + 0);
            float4 c1 = *(const float4*)(Br + 4);
            float4 c2 = *(const float4*)(Br + 8);
            float4 c3 = *(const float4*)(Br + 12);
            uint4 H0, L0, H1, L1;
            split8(radd4(a0, c0), radd4(a1, c1), H0, L0);   // kh=0
            split8(radd4(a2, c2), radd4(a3, c3), H1, L1);   // kh=1
            *(uint4*)(&Ts[u_h0]) = H0;
            *(uint4*)(&Ts[u_h1]) = H1;
            *(uint4*)(&Ts[u_l0]) = L0;
            *(uint4*)(&Ts[u_l1]) = L1;
        } else {
            uint4 z = make_uint4(0u, 0u, 0u, 0u);
            *(uint4*)(&Ts[u_h0]) = z;
            *(uint4*)(&Ts[u_h1]) = z;
            *(uint4*)(&Ts[u_l0]) = z;
            *(uint4*)(&Ts[u_l1]) = z;
        }
    }
    __syncthreads();   // the only block barrier

    const int lane = t & 63;
    const int wv   = t >> 6;             // wave's 32-col tile
    const int m    = lane & 31;
    const int kh   = lane >> 5;

    f32x16 acc = {0,0,0,0,0,0,0,0,0,0,0,0,0,0,0,0};

    // W2f: c*4096 + wv*1024 + p*512 + lane*8
    const short* Wp = W2l + (size_t)wv * 1024 + (size_t)lane * 8;

    short8v bh = *(const short8v*)(Wp);
    short8v bl = *(const short8v*)(Wp + 512);
    short8v ah = *(const short8v*)(&Ts[(size_t)lane * 8]);          // c=0, p0
    short8v al = *(const short8v*)(&Ts[(size_t)(512 + lane) * 8]);  // c=0, p1

#pragma unroll
    for (int c = 0; c < 8; ++c) {
        short8v nbh, nbl, nah, nal;
        if (c < 7) {                     // prefetch chunk c+1
            const int cn = c + 1;
            nbh = *(const short8v*)(Wp + (size_t)cn * 4096);
            nbl = *(const short8v*)(Wp + (size_t)cn * 4096 + 512);
            nah = *(const short8v*)(&Ts[(size_t)((cn * 64 + lane) ^ cn) * 8]);
            nal = *(const short8v*)(&Ts[(size_t)((512 + cn * 64 + lane) ^ cn) * 8]);
        }
        acc = __builtin_amdgcn_mfma_f32_32x32x16_bf16(ah, bh, acc, 0, 0, 0);
        acc = __builtin_amdgcn_mfma_f32_32x32x16_bf16(al, bh, acc, 0, 0, 0);
        acc = __builtin_amdgcn_mfma_f32_32x32x16_bf16(ah, bl, acc, 0, 0, 0);
        if (c < 7) { bh = nbh; bl = nbl; ah = nah; al = nal; }
    }

    // ---- aggregation ----
    const int col = wv * 32 + m;
    const int d_first = dsts[0];
    const int d_last  = dsts[EB7 - 1];
    if (d_first == d_last) {             // whole block one dst (sorted slots)
        if (d_first >= 0) {
            float m0 = fmaxf(acc[0], acc[1]);
            float m1 = fmaxf(acc[2], acc[3]);
            float m2 = fmaxf(acc[4], acc[5]);
            float m3 = fmaxf(acc[6], acc[7]);
            float m4 = fmaxf(acc[8], acc[9]);
            float m5 = fmaxf(acc[10], acc[11]);
            float m6 = fmaxf(acc[12], acc[13]);
            float m7 = fmaxf(acc[14], acc[15]);
            m0 = fmaxf(m0, m1); m2 = fmaxf(m2, m3);
            m4 = fmaxf(m4, m5); m6 = fmaxf(m6, m7);
            m0 = fmaxf(m0, m2); m4 = fmaxf(m4, m6);
            m0 = fmaxf(m0, m4);
            atomicMax(&enc[(size_t)d_first * HIDDEN + col], encf(m0));
        }
    } else {
        float run = -3.4e38f;
        int curd = dsts[4 * kh];
#pragma unroll
        for (int r = 0; r < 16; ++r) {
            const int er = (r & 3) + 8 * (r >> 2) + 4 * kh;
            int d = dsts[er];
            if (d != curd) {
                if (curd >= 0)
                    atomicMax(&enc[(size_t)curd * HIDDEN + col], encf(run));
                curd = d;
                run = -3.4e38f;
            }
            run = fmaxf(run, acc[r]);
        }
        if (curd >= 0)
            atomicMax(&enc[(size_t)curd * HIDDEN + col], encf(run));
    }
}

// ---------------- launch ----------------
extern "C" void kernel_launch(void* const* d_in, const int* in_sizes, int n_in,
                              void* d_out, int out_size, void* d_ws, size_t ws_size,
                              hipStream_t stream)
{
    const float* x     = (const float*)d_in[0];
    const int*   ei    = (const int*)d_in[1];
    const float* W_emb = (const float*)d_in[2];
    const float* b_emb = (const float*)d_in[3];
    const float* W1    = (const float*)d_in[4];
    const float* b1    = (const float*)d_in[5];
    const float* W2    = (const float*)d_in[6];
    const float* b2    = (const float*)d_in[7];
    const float* W_fc  = (const float*)d_in[8];
    const float* b_fc  = (const float*)d_in[9];
    float* out = (float*)d_out;

    char* p = (char*)d_ws;
    auto alloc = [&](size_t bytes) {
        char* r = p;
        p += (bytes + 255) & ~(size_t)255;
        return r;
    };
    float* h    = (float*)alloc((size_t)N_NODES * HIDDEN * 4);
    float* Ab   = (float*)alloc((size_t)N_NODES * HIDDEN * 4);
    float* Bb   = (float*)alloc((size_t)N_NODES * HIDDEN * 4);
    unsigned int* enc = (unsigned int*)alloc((size_t)N_NODES * HIDDEN * 4);
    float* Wa   = (float*)alloc((size_t)NUM_LAYERS * 16384 * 4);
    float* Wb   = (float*)alloc((size_t)NUM_LAYERS * 16384 * 4);
    short* W2f  = (short*)alloc((size_t)NUM_LAYERS * 32768 * 2);
    int* cursor = (int*)alloc(N_NODES * 4);
    int* cnt    = (int*)alloc(N_NODES * 4);
    int* esrc   = (int*)alloc((size_t)NT * 4);
    int* edst   = (int*)alloc((size_t)NT * 4);
    int* srcN   = (int*)alloc((size_t)N_EDGES * 4);
    int* dstN   = (int*)alloc((size_t)N_EDGES * 4);
    int* flag   = (int*)alloc(4);

    const int EBLK = (N_EDGES + 255) / 256;

    k_detect<<<1, 256, 0, stream>>>(ei, flag);
    k_normalize<<<EBLK, 256, 0, stream>>>(ei, flag, srcN, dstN);
    k_zero<<<(N_NODES + 255) / 256, 256, 0, stream>>>(cnt, N_NODES);
    k_count<<<EBLK, 256, 0, stream>>>(dstN, cnt);
    k_scan<<<1, 256, 0, stream>>>(cnt, cursor);
    k_scatter<<<EBLK, 256, 0, stream>>>(srcN, dstN, cursor, esrc, edst);
    k_selfloop<<<(N_NODES + 255) / 256, 256, 0, stream>>>(cursor, esrc, edst);
    k_prepw<<<(NUM_LAYERS * 16384 + 255) / 256, 256, 0, stream>>>(W1, Wa, Wb);
    k_prepw2<<<(NUM_LAYERS * 16384 + 255) / 256, 256, 0, stream>>>(W2, W2f);

    const int GB32 = (N_NODES + 31) / 32;         // 313
    const int EG7  = (NT + EB7 - 1) / EB7;        // 20313
    const int NZ   = (N_NODES * HIDDEN + 255) / 256;

    k_zero<<<NZ, 256, 0, stream>>>((int*)enc, N_NODES * HIDDEN);
    // embedding: h = x @ W_emb + b_emb
    k_gemm32<NODE_DIM, false><<<GB32, 256, 0, stream>>>(
        x, nullptr, nullptr, W_emb, nullptr, b_emb, h, nullptr, N_NODES);

    for (int l = 0; l < NUM_LAYERS; ++l) {
        if (l == 0) {
            k_gemm32<HIDDEN, true><<<GB32, 256, 0, stream>>>(
                h, nullptr, nullptr, Wa + l * 16384, Wb + l * 16384,
                b1 + l * 128, Ab, Bb, N_NODES);
        } else {
            k_gemm32<HIDDEN, true><<<GB32, 256, 0, stream>>>(
                nullptr, enc, b2 + (l - 1) * 128, Wa + l * 16384, Wb + l * 16384,
                b1 + l * 128, Ab, Bb, N_NODES);
        }
        k_edge7<<<EG7, 256, 0, stream>>>(Ab, Bb, esrc, edst,
                                         W2f + (size_t)l * 32768, enc);
    }
    // final fc decodes enc(layer 3) + b2[3], multiplies W_fc
    k_gemm32<HIDDEN, false><<<GB32, 256, 0, stream>>>(
        nullptr, enc, b2 + 3 * 128, W_fc, nullptr, b_fc, out, nullptr, N_NODES);
}

// Round 8
// 575.098 us; speedup vs baseline: 1.3917x; 1.3917x over previous
//
#include <hip/hip_runtime.h>

#define N_NODES 10000
#define N_EDGES 640000
#define NODE_DIM 64
#define HIDDEN 128
#define NUM_LAYERS 4
#define NT (N_EDGES + N_NODES)   // 650000 edge slots incl. self loops
#define EB8 64                   // edge slots per block in k_edge8

typedef __attribute__((ext_vector_type(8))) short short8v;
typedef __attribute__((ext_vector_type(16))) float f32x16;

// ---------------- edge dtype detection / normalization ----------------
__global__ void k_detect(const int* __restrict__ ei, int* __restrict__ flag)
{
    __shared__ int nz;
    if (threadIdx.x == 0) nz = 0;
    __syncthreads();
    int found = 0;
    for (int k = threadIdx.x; k < 2048; k += 256) {
        int pos = 2 * (k * 156) + 1;
        if (ei[pos] != 0) found = 1;
    }
    if (found) atomicOr(&nz, 1);
    __syncthreads();
    if (threadIdx.x == 0) flag[0] = nz;          // 1 = int32 layout, 0 = int64
}

__global__ void k_normalize(const int* __restrict__ ei, const int* __restrict__ flag,
                            int* __restrict__ srcN, int* __restrict__ dstN)
{
    int e = blockIdx.x * 256 + threadIdx.x;
    if (e >= N_EDGES) return;
    if (flag[0]) {
        srcN[e] = ei[e];
        dstN[e] = ei[N_EDGES + e];
    } else {
        srcN[e] = ei[2 * e];
        dstN[e] = ei[2 * (N_EDGES + e)];
    }
}

__global__ void k_zero(int* __restrict__ p, int n)
{
    int i = blockIdx.x * 256 + threadIdx.x;
    if (i < n) p[i] = 0;
}

__global__ void k_count(const int* __restrict__ dstN, int* __restrict__ cnt)
{
    int e = blockIdx.x * 256 + threadIdx.x;
    if (e < N_EDGES) atomicAdd(&cnt[dstN[e]], 1);
}

__global__ void k_scan(const int* __restrict__ cnt, int* __restrict__ cursor)
{
    __shared__ int part[256];
    const int t = threadIdx.x;
    const int CH = (N_NODES + 255) / 256;        // 40
    int lo = t * CH, hi = min(N_NODES, lo + CH);
    int s = 0;
    for (int i = lo; i < hi; ++i) s += cnt[i] + 1;
    part[t] = s;
    __syncthreads();
    for (int off = 1; off < 256; off <<= 1) {
        int v = (t >= off) ? part[t - off] : 0;
        __syncthreads();
        part[t] += v;
        __syncthreads();
    }
    int base = (t == 0) ? 0 : part[t - 1];
    for (int i = lo; i < hi; ++i) {
        cursor[i] = base;
        base += cnt[i] + 1;
    }
}

__global__ void k_scatter(const int* __restrict__ srcN, const int* __restrict__ dstN,
                          int* __restrict__ cursor,
                          int* __restrict__ esrc, int* __restrict__ edst)
{
    int e = blockIdx.x * 256 + threadIdx.x;
    if (e < N_EDGES) {
        int d = dstN[e];
        int pos = atomicAdd(&cursor[d], 1);
        esrc[pos] = srcN[e];
        edst[pos] = d;
    }
}

__global__ void k_selfloop(int* __restrict__ cursor,
                           int* __restrict__ esrc, int* __restrict__ edst)
{
    int n = blockIdx.x * 256 + threadIdx.x;
    if (n < N_NODES) {
        int pos = atomicAdd(&cursor[n], 1);
        esrc[pos] = n;
        edst[pos] = n;
    }
}

// Wa = W1[:,:128,:] - W1[:,128:,:] (x_i side);  Wb = W1[:,128:,:] (x_j side)
__global__ void k_prepw(const float* __restrict__ W1, float* __restrict__ Wa,
                        float* __restrict__ Wb)
{
    int i = blockIdx.x * 256 + threadIdx.x;      // over L*128*128
    if (i >= NUM_LAYERS * 128 * 128) return;
    int l = i >> 14, rem = i & 16383;
    float top = W1[l * 32768 + rem];
    float bot = W1[l * 32768 + 16384 + rem];
    Wa[i] = top - bot;
    Wb[i] = bot;
}

__device__ __forceinline__ unsigned short bf16rne(float f)
{
    unsigned int u = __float_as_uint(f);
    unsigned int r = u + 0x7FFFu + ((u >> 16) & 1u);
    return (unsigned short)(r >> 16);
}

// W2 -> fragment-linear hi/lo bf16, lane-contiguous:
// W2f[l][c][tile][p][lane][j]  (lane = kh*32+m holds W2[k=16c+8kh+j][n=32tile+m])
__global__ void k_prepw2(const float* __restrict__ W2, short* __restrict__ W2f)
{
    int i = blockIdx.x * 256 + threadIdx.x;      // over L*128*128
    if (i >= NUM_LAYERS * 128 * 128) return;
    int l = i >> 14, rem = i & 16383;            // rem = k*128 + n
    int k = rem >> 7, n = rem & 127;
    float w = W2[i];
    unsigned short hs = bf16rne(w);
    float hf = __uint_as_float((unsigned int)hs << 16);
    unsigned short ls = bf16rne(w - hf);
    int c = k >> 4, kh = (k >> 3) & 1, j = k & 7;
    int tile = n >> 5, m = n & 31;
    int lane = kh * 32 + m;
    size_t base = (size_t)l * 32768 + c * 4096 + tile * 1024 + lane * 8 + j;
    W2f[base]       = (short)hs;
    W2f[base + 512] = (short)ls;
}

__device__ __forceinline__ unsigned int encf(float f)
{
    unsigned int b = __float_as_uint(f);
    return b ^ ((unsigned int)((int)b >> 31) | 0x80000000u);
}

__device__ __forceinline__ float decenc(unsigned int u)
{
    unsigned int bits = (u & 0x80000000u) ? (u ^ 0x80000000u) : ~u;
    return __uint_as_float(bits);
}

// relu(a+b), then split to bf16 hi (trunc) + lo (RNE residual), pack 4 floats
// into uint2 H (hi words) and uint2 L (lo words), element order low-to-high.
__device__ __forceinline__ void radd_split4(float4 a, float4 b, uint2& H, uint2& L)
{
    float f0 = fmaxf(a.x + b.x, 0.f), f1 = fmaxf(a.y + b.y, 0.f);
    float f2 = fmaxf(a.z + b.z, 0.f), f3 = fmaxf(a.w + b.w, 0.f);
    unsigned int u0 = __float_as_uint(f0), u1 = __float_as_uint(f1);
    unsigned int u2 = __float_as_uint(f2), u3 = __float_as_uint(f3);
    H.x = (u1 & 0xFFFF0000u) | (u0 >> 16);
    H.y = (u3 & 0xFFFF0000u) | (u2 >> 16);
    float r0 = f0 - __uint_as_float(u0 & 0xFFFF0000u);
    float r1 = f1 - __uint_as_float(u1 & 0xFFFF0000u);
    float r2 = f2 - __uint_as_float(u2 & 0xFFFF0000u);
    float r3 = f3 - __uint_as_float(u3 & 0xFFFF0000u);
    unsigned int v0 = __float_as_uint(r0) ;
    unsigned int v1 = __float_as_uint(r1);
    unsigned int v2 = __float_as_uint(r2);
    unsigned int v3 = __float_as_uint(r3);
    v0 = v0 + 0x7FFFu + ((v0 >> 16) & 1u);
    v1 = v1 + 0x7FFFu + ((v1 >> 16) & 1u);
    v2 = v2 + 0x7FFFu + ((v2 >> 16) & 1u);
    v3 = v3 + 0x7FFFu + ((v3 >> 16) & 1u);
    L.x = (v0 >> 16) | (v1 & 0xFFFF0000u);
    L.y = (v2 >> 16) | (v3 & 0xFFFF0000u);
}

// -------- node GEMM, 64 rows x 64 cols per block (grid = 2 * row-tiles) --------
// X = (DEC ? decode(enc)+bprev : Xf); CA = X@WA[:,ch*64:+64] + biasA;
// if HASB: CB = X@WB[:, same cols]. enc is NOT modified (zeroed separately).
template <int K, bool HASB, bool DEC>
__global__ __launch_bounds__(256) void k_gemm64(
    const float* __restrict__ Xf, const unsigned int* __restrict__ enc,
    const float* __restrict__ bprev,
    const float* __restrict__ WA, const float* __restrict__ WB,
    const float* __restrict__ biasA,
    float* __restrict__ CA, float* __restrict__ CB, int M)
{
    constexpr int LDX = K + 4;
    __shared__ float Xs[64 * LDX];
    const int t = threadIdx.x;
    const int row0 = (blockIdx.x >> 1) * 64;
    const int ch   = (blockIdx.x & 1) * 64;      // col half
    constexpr int F4R = K / 4;
    for (int i = t; i < 64 * F4R; i += 256) {
        int r = i / F4R, f = i % F4R;
        int gr = row0 + r;
        float4 v = make_float4(0.f, 0.f, 0.f, 0.f);
        if (gr < M) {
            if constexpr (DEC) {
                uint4 u = *(const uint4*)(enc + (size_t)gr * K + 4 * f);
                v.x = decenc(u.x) + bprev[4 * f + 0];
                v.y = decenc(u.y) + bprev[4 * f + 1];
                v.z = decenc(u.z) + bprev[4 * f + 2];
                v.w = decenc(u.w) + bprev[4 * f + 3];
            } else {
                v = *(const float4*)(Xf + (size_t)gr * K + 4 * f);
            }
        }
        *(float4*)(Xs + r * LDX + 4 * f) = v;
    }
    __syncthreads();

    const int rg = t >> 4, cg = t & 15;      // 4 rows x 4 cols per thread
    float accA[4][4], accB[4][4];
#pragma unroll
    for (int i = 0; i < 4; ++i)
#pragma unroll
        for (int j = 0; j < 4; ++j) { accA[i][j] = 0.f; accB[i][j] = 0.f; }

#pragma unroll 4
    for (int k = 0; k < K; ++k) {
        float4 wa = *(const float4*)(WA + k * 128 + ch + cg * 4);
        float xs[4];
#pragma unroll
        for (int i = 0; i < 4; ++i) xs[i] = Xs[(rg * 4 + i) * LDX + k];
#pragma unroll
        for (int i = 0; i < 4; ++i) {
            accA[i][0] += xs[i] * wa.x; accA[i][1] += xs[i] * wa.y;
            accA[i][2] += xs[i] * wa.z; accA[i][3] += xs[i] * wa.w;
        }
        if constexpr (HASB) {
            float4 wb = *(const float4*)(WB + k * 128 + ch + cg * 4);
#pragma unroll
            for (int i = 0; i < 4; ++i) {
                accB[i][0] += xs[i] * wb.x; accB[i][1] += xs[i] * wb.y;
                accB[i][2] += xs[i] * wb.z; accB[i][3] += xs[i] * wb.w;
            }
        }
    }
    float4 b = *(const float4*)(biasA + ch + cg * 4);
#pragma unroll
    for (int i = 0; i < 4; ++i) {
        int r = row0 + rg * 4 + i;
        if (r < M) {
            *(float4*)(CA + (size_t)r * 128 + ch + cg * 4) =
                make_float4(accA[i][0] + b.x, accA[i][1] + b.y,
                            accA[i][2] + b.z, accA[i][3] + b.w);
            if constexpr (HASB) {
                *(float4*)(CB + (size_t)r * 128 + ch + cg * 4) =
                    make_float4(accB[i][0], accB[i][1], accB[i][2], accB[i][3]);
            }
        }
    }
}

// ---------------- EdgeConv v8: EB=64, all-B-in-registers k-loop ----------------
// Wave wv owns col-tile [wv*32,+32) x BOTH 32-edge slabs. The wave's FULL B
// (8 chunks x hi/lo = 16 short8v = 64 VGPR) is loaded from W2f BEFORE staging
// so HBM/L2 latency hides under staging VALU; the k-loop is pure ds_read+MFMA.
// Fragment-linear swizzled LDS as R5/R6 (0 conflicts measured).
__global__ __launch_bounds__(256, 4) void k_edge8(
    const float* __restrict__ A, const float* __restrict__ Bm,
    const int* __restrict__ esrc, const int* __restrict__ edst,
    const short* __restrict__ W2l, unsigned int* __restrict__ enc)
{
    __shared__ __align__(16) short Ts[2048 * 8];   // 32 KB, fragment-linear
    __shared__ int dsts[EB8];

    const int t = threadIdx.x;
    const int lane = t & 63;
    const int wv   = t >> 6;
    // bijective XCD-chunked block swizzle (m204 form)
    const int nwg = (int)gridDim.x;
    const int orig = (int)blockIdx.x;
    const int xcd = orig & 7, idx = orig >> 3;
    const int qq = nwg >> 3, rr = nwg & 7;
    const int bid = (xcd < rr ? xcd * (qq + 1) : rr * (qq + 1) + (xcd - rr) * qq) + idx;
    const int s0 = bid * EB8;

    // ---- issue the wave's full B-fragment set first (latency hides under staging) ----
    const short* Wp = W2l + (size_t)wv * 1024 + (size_t)lane * 8;
    short8v bfh[8], bfl[8];
#pragma unroll
    for (int c = 0; c < 8; ++c) {
        bfh[c] = *(const short8v*)(Wp + (size_t)c * 4096);
        bfl[c] = *(const short8v*)(Wp + (size_t)c * 4096 + 512);
    }

    // ---- stage T hi/lo (4 threads per edge slot; quad = one 64B line per r) ----
    {
        const int row = t >> 2;          // edge slot within block
        const int q   = t & 3;
        const int slot = s0 + row;
        int dst = -1, src = 0;
        if (slot < NT) { dst = edst[slot]; src = esrc[slot]; }
        if (q == 0) dsts[row] = dst;
        const int sfrag = row >> 5;      // slab
        const int mrow  = row & 31;
        const int kh    = q >> 1;
        const int half  = q & 1;
        const int lbase = kh * 32 + mrow;

        if (dst >= 0) {
            const float* Ar = A  + (size_t)dst * HIDDEN + q * 4;
            const float* Br = Bm + (size_t)src * HIDDEN + q * 4;
#pragma unroll
            for (int r = 0; r < 8; ++r) {
                float4 av = *(const float4*)(Ar + r * 16);
                float4 bv = *(const float4*)(Br + r * 16);
                uint2 H, L;
                radd_split4(av, bv, H, L);
                const int c  = r;
                const int ih = ((sfrag)     * 8 + c) * 64 + lbase;   // p=0
                const int il = ((2 + sfrag) * 8 + c) * 64 + lbase;   // p=1
                *(uint2*)(&Ts[(size_t)(ih ^ c) * 8 + half * 4]) = H;
                *(uint2*)(&Ts[(size_t)(il ^ c) * 8 + half * 4]) = L;
            }
        } else {
            uint2 z = make_uint2(0u, 0u);
#pragma unroll
            for (int r = 0; r < 8; ++r) {
                const int c  = r;
                const int ih = ((sfrag)     * 8 + c) * 64 + lbase;
                const int il = ((2 + sfrag) * 8 + c) * 64 + lbase;
                *(uint2*)(&Ts[(size_t)(ih ^ c) * 8 + half * 4]) = z;
                *(uint2*)(&Ts[(size_t)(il ^ c) * 8 + half * 4]) = z;
            }
        }
    }
    __syncthreads();   // the only block barrier

    f32x16 acc0 = {0,0,0,0,0,0,0,0,0,0,0,0,0,0,0,0};   // slab 0 (rows 0-31)
    f32x16 acc1 = {0,0,0,0,0,0,0,0,0,0,0,0,0,0,0,0};   // slab 1 (rows 32-63)

#pragma unroll
    for (int c = 0; c < 8; ++c) {
        // A-fragment unit indices: ((p*2+s)*8 + c)*64 + lane, stored at idx^c
        short8v ah0 = *(const short8v*)(&Ts[(size_t)(((0 * 8 + c) * 64 + lane) ^ c) * 8]);
        short8v ah1 = *(const short8v*)(&Ts[(size_t)(((1 * 8 + c) * 64 + lane) ^ c) * 8]);
        short8v al0 = *(const short8v*)(&Ts[(size_t)(((2 * 8 + c) * 64 + lane) ^ c) * 8]);
        short8v al1 = *(const short8v*)(&Ts[(size_t)(((3 * 8 + c) * 64 + lane) ^ c) * 8]);
        acc0 = __builtin_amdgcn_mfma_f32_32x32x16_bf16(ah0, bfh[c], acc0, 0, 0, 0);
        acc0 = __builtin_amdgcn_mfma_f32_32x32x16_bf16(al0, bfh[c], acc0, 0, 0, 0);
        acc0 = __builtin_amdgcn_mfma_f32_32x32x16_bf16(ah0, bfl[c], acc0, 0, 0, 0);
        acc1 = __builtin_amdgcn_mfma_f32_32x32x16_bf16(ah1, bfh[c], acc1, 0, 0, 0);
        acc1 = __builtin_amdgcn_mfma_f32_32x32x16_bf16(al1, bfh[c], acc1, 0, 0, 0);
        acc1 = __builtin_amdgcn_mfma_f32_32x32x16_bf16(ah1, bfl[c], acc1, 0, 0, 0);
    }

    // ---- aggregation ----
    const int m   = lane & 31;
    const int kh  = lane >> 5;
    const int col = wv * 32 + m;
    const int d_first = dsts[0];
    const int d_last  = dsts[EB8 - 1];
    if (d_first == d_last) {             // whole block one dst (sorted slots)
        if (d_first >= 0) {
            float mx = fmaxf(acc0[0], acc1[0]);
#pragma unroll
            for (int r = 1; r < 16; ++r)
                mx = fmaxf(mx, fmaxf(acc0[r], acc1[r]));
            atomicMax(&enc[(size_t)d_first * HIDDEN + col], encf(mx));
        }
    } else {
        {
            float run = -3.4e38f;
            int curd = dsts[4 * kh];
#pragma unroll
            for (int r = 0; r < 16; ++r) {
                const int er = (r & 3) + 8 * (r >> 2) + 4 * kh;
                int d = dsts[er];
                if (d != curd) {
                    if (curd >= 0)
                        atomicMax(&enc[(size_t)curd * HIDDEN + col], encf(run));
                    curd = d;
                    run = -3.4e38f;
                }
                run = fmaxf(run, acc0[r]);
            }
            if (curd >= 0)
                atomicMax(&enc[(size_t)curd * HIDDEN + col], encf(run));
        }
        {
            float run = -3.4e38f;
            int curd = dsts[32 + 4 * kh];
#pragma unroll
            for (int r = 0; r < 16; ++r) {
                const int er = 32 + (r & 3) + 8 * (r >> 2) + 4 * kh;
                int d = dsts[er];
                if (d != curd) {
                    if (curd >= 0)
                        atomicMax(&enc[(size_t)curd * HIDDEN + col], encf(run));
                    curd = d;
                    run = -3.4e38f;
                }
                run = fmaxf(run, acc1[r]);
            }
            if (curd >= 0)
                atomicMax(&enc[(size_t)curd * HIDDEN + col], encf(run));
        }
    }
}

// ---------------- launch ----------------
extern "C" void kernel_launch(void* const* d_in, const int* in_sizes, int n_in,
                              void* d_out, int out_size, void* d_ws, size_t ws_size,
                              hipStream_t stream)
{
    const float* x     = (const float*)d_in[0];
    const int*   ei    = (const int*)d_in[1];
    const float* W_emb = (const float*)d_in[2];
    const float* b_emb = (const float*)d_in[3];
    const float* W1    = (const float*)d_in[4];
    const float* b1    = (const float*)d_in[5];
    const float* W2    = (const float*)d_in[6];
    const float* b2    = (const float*)d_in[7];
    const float* W_fc  = (const float*)d_in[8];
    const float* b_fc  = (const float*)d_in[9];
    float* out = (float*)d_out;

    char* p = (char*)d_ws;
    auto alloc = [&](size_t bytes) {
        char* r = p;
        p += (bytes + 255) & ~(size_t)255;
        return r;
    };
    float* h    = (float*)alloc((size_t)N_NODES * HIDDEN * 4);
    float* Ab   = (float*)alloc((size_t)N_NODES * HIDDEN * 4);
    float* Bb   = (float*)alloc((size_t)N_NODES * HIDDEN * 4);
    unsigned int* enc = (unsigned int*)alloc((size_t)N_NODES * HIDDEN * 4);
    float* Wa   = (float*)alloc((size_t)NUM_LAYERS * 16384 * 4);
    float* Wb   = (float*)alloc((size_t)NUM_LAYERS * 16384 * 4);
    short* W2f  = (short*)alloc((size_t)NUM_LAYERS * 32768 * 2);
    int* cursor = (int*)alloc(N_NODES * 4);
    int* cnt    = (int*)alloc(N_NODES * 4);
    int* esrc   = (int*)alloc((size_t)NT * 4);
    int* edst   = (int*)alloc((size_t)NT * 4);
    int* srcN   = (int*)alloc((size_t)N_EDGES * 4);
    int* dstN   = (int*)alloc((size_t)N_EDGES * 4);
    int* flag   = (int*)alloc(4);

    const int EBLK = (N_EDGES + 255) / 256;

    k_detect<<<1, 256, 0, stream>>>(ei, flag);
    k_normalize<<<EBLK, 256, 0, stream>>>(ei, flag, srcN, dstN);
    k_zero<<<(N_NODES + 255) / 256, 256, 0, stream>>>(cnt, N_NODES);
    k_count<<<EBLK, 256, 0, stream>>>(dstN, cnt);
    k_scan<<<1, 256, 0, stream>>>(cnt, cursor);
    k_scatter<<<EBLK, 256, 0, stream>>>(srcN, dstN, cursor, esrc, edst);
    k_selfloop<<<(N_NODES + 255) / 256, 256, 0, stream>>>(cursor, esrc, edst);
    k_prepw<<<(NUM_LAYERS * 16384 + 255) / 256, 256, 0, stream>>>(W1, Wa, Wb);
    k_prepw2<<<(NUM_LAYERS * 16384 + 255) / 256, 256, 0, stream>>>(W2, W2f);

    const int GB  = 2 * ((N_NODES + 63) / 64);    // 314 (row-tiles x col-halves)
    const int EG  = (NT + EB8 - 1) / EB8;         // 10157
    const int NZ  = (N_NODES * HIDDEN + 255) / 256;

    k_zero<<<NZ, 256, 0, stream>>>((int*)enc, N_NODES * HIDDEN);
    // embedding: h = x @ W_emb + b_emb
    k_gemm64<NODE_DIM, false, false><<<GB, 256, 0, stream>>>(
        x, nullptr, nullptr, W_emb, nullptr, b_emb, h, nullptr, N_NODES);

    for (int l = 0; l < NUM_LAYERS; ++l) {
        if (l == 0) {
            k_gemm64<HIDDEN, true, false><<<GB, 256, 0, stream>>>(
                h, nullptr, nullptr, Wa + l * 16384, Wb + l * 16384,
                b1 + l * 128, Ab, Bb, N_NODES);
        } else {
            k_gemm64<HIDDEN, true, true><<<GB, 256, 0, stream>>>(
                nullptr, enc, b2 + (l - 1) * 128, Wa + l * 16384, Wb + l * 16384,
                b1 + l * 128, Ab, Bb, N_NODES);
            k_zero<<<NZ, 256, 0, stream>>>((int*)enc, N_NODES * HIDDEN);
        }
        k_edge8<<<EG, 256, 0, stream>>>(Ab, Bb, esrc, edst,
                                        W2f + (size_t)l * 32768, enc);
    }
    // final fc decodes enc(layer 3) + b2[3], multiplies W_fc
    k_gemm64<HIDDEN, false, true><<<GB, 256, 0, stream>>>(
        nullptr, enc, b2 + 3 * 128, W_fc, nullptr, b_fc, out, nullptr, N_NODES);
}

// Round 9
// 561.569 us; speedup vs baseline: 1.4252x; 1.0241x over previous
//
#include <hip/hip_runtime.h>

#define N_NODES 10000
#define N_EDGES 640000
#define NODE_DIM 64
#define HIDDEN 128
#define NUM_LAYERS 4
#define NT (N_EDGES + N_NODES)   // 650000 edge slots incl. self loops
#define EB8 64                   // edge slots per block in k_edge9

typedef __attribute__((ext_vector_type(8))) short short8v;
typedef __attribute__((ext_vector_type(16))) float f32x16;

// ---------------- init: zero cnt + enc0, detect edge dtype ----------------
// edge_index may arrive as int32 or int64 (values < 10000 so high words = 0).
__global__ void k_init(const int* __restrict__ ei, int* __restrict__ flag,
                       int* __restrict__ cnt, unsigned int* __restrict__ enc0)
{
    int gid = blockIdx.x * 256 + threadIdx.x;
    if (gid < N_NODES) cnt[gid] = 0;
    for (int i = gid; i < N_NODES * HIDDEN; i += (int)gridDim.x * 256)
        enc0[i] = 0u;
    if (blockIdx.x == 0) {
        __shared__ int nz;
        if (threadIdx.x == 0) nz = 0;
        __syncthreads();
        int found = 0;
        for (int k = threadIdx.x; k < 2048; k += 256) {
            int pos = 2 * (k * 156) + 1;        // odd, < 640000: valid both layouts
            if (ei[pos] != 0) found = 1;
        }
        if (found) atomicOr(&nz, 1);
        __syncthreads();
        if (threadIdx.x == 0) flag[0] = nz;      // 1 = int32 layout, 0 = int64
    }
}

// ---------------- normalize + degree count (fused) ----------------
__global__ void k_norm_count(const int* __restrict__ ei, const int* __restrict__ flag,
                             int* __restrict__ srcN, int* __restrict__ dstN,
                             int* __restrict__ cnt)
{
    int e = blockIdx.x * 256 + threadIdx.x;
    if (e >= N_EDGES) return;
    int s, d;
    if (flag[0]) { s = ei[e];     d = ei[N_EDGES + e]; }
    else         { s = ei[2 * e]; d = ei[2 * (N_EDGES + e)]; }
    srcN[e] = s;
    dstN[e] = d;
    atomicAdd(&cnt[d], 1);
}

// single-block exclusive scan over (cnt[i]+1) -> cursor (self loop included)
__global__ void k_scan(const int* __restrict__ cnt, int* __restrict__ cursor)
{
    __shared__ int part[256];
    const int t = threadIdx.x;
    const int CH = (N_NODES + 255) / 256;        // 40
    int lo = t * CH, hi = min(N_NODES, lo + CH);
    int s = 0;
    for (int i = lo; i < hi; ++i) s += cnt[i] + 1;
    part[t] = s;
    __syncthreads();
    for (int off = 1; off < 256; off <<= 1) {
        int v = (t >= off) ? part[t - off] : 0;
        __syncthreads();
        part[t] += v;
        __syncthreads();
    }
    int base = (t == 0) ? 0 : part[t - 1];
    for (int i = lo; i < hi; ++i) {
        cursor[i] = base;
        base += cnt[i] + 1;
    }
}

// scatter edges + self loops (fused)
__global__ void k_scatter_all(const int* __restrict__ srcN, const int* __restrict__ dstN,
                              int* __restrict__ cursor,
                              int* __restrict__ esrc, int* __restrict__ edst)
{
    int e = blockIdx.x * 256 + threadIdx.x;
    if (e >= NT) return;
    int s, d;
    if (e < N_EDGES) { s = srcN[e]; d = dstN[e]; }
    else             { s = e - N_EDGES; d = s; }
    int pos = atomicAdd(&cursor[d], 1);
    esrc[pos] = s;
    edst[pos] = d;
}

__device__ __forceinline__ unsigned short bf16rne(float f)
{
    unsigned int u = __float_as_uint(f);
    unsigned int r = u + 0x7FFFu + ((u >> 16) & 1u);
    return (unsigned short)(r >> 16);
}

// fused weight prep:
//   Wa = W1[:,:128,:] - W1[:,128:,:];  Wb = W1[:,128:,:]
//   W2 -> fragment-linear hi/lo bf16 W2f[l][c][tile][p][lane][j]
__global__ void k_prepww(const float* __restrict__ W1, const float* __restrict__ W2,
                         float* __restrict__ Wa, float* __restrict__ Wb,
                         short* __restrict__ W2f)
{
    int i = blockIdx.x * 256 + threadIdx.x;      // over L*128*128
    if (i >= NUM_LAYERS * 128 * 128) return;
    int l = i >> 14, rem = i & 16383;            // rem = k*128 + n
    float top = W1[l * 32768 + rem];
    float bot = W1[l * 32768 + 16384 + rem];
    Wa[i] = top - bot;
    Wb[i] = bot;

    int k = rem >> 7, n = rem & 127;
    float w = W2[i];
    unsigned short hs = bf16rne(w);
    float hf = __uint_as_float((unsigned int)hs << 16);
    unsigned short ls = bf16rne(w - hf);
    int c = k >> 4, kh = (k >> 3) & 1, j = k & 7;
    int tile = n >> 5, m = n & 31;
    int lane = kh * 32 + m;
    size_t base = (size_t)l * 32768 + c * 4096 + tile * 1024 + lane * 8 + j;
    W2f[base]       = (short)hs;
    W2f[base + 512] = (short)ls;
}

__device__ __forceinline__ unsigned int encf(float f)
{
    unsigned int b = __float_as_uint(f);
    return b ^ ((unsigned int)((int)b >> 31) | 0x80000000u);
}

__device__ __forceinline__ float decenc(unsigned int u)
{
    unsigned int bits = (u & 0x80000000u) ? (u ^ 0x80000000u) : ~u;
    return __uint_as_float(bits);
}

// relu(a+b) -> bf16 hi (trunc) + lo (trunc of residual), packed pairs.
// Error: hi+lo reconstructs to 2^-16 relative — same order as the dropped
// tl*wl MFMA term. Saves the RNE adjustment VALU ops (hot path).
__device__ __forceinline__ void radd_split4(float4 a, float4 b, uint2& H, uint2& L)
{
    float f0 = fmaxf(a.x + b.x, 0.f), f1 = fmaxf(a.y + b.y, 0.f);
    float f2 = fmaxf(a.z + b.z, 0.f), f3 = fmaxf(a.w + b.w, 0.f);
    unsigned int u0 = __float_as_uint(f0), u1 = __float_as_uint(f1);
    unsigned int u2 = __float_as_uint(f2), u3 = __float_as_uint(f3);
    H.x = (u1 & 0xFFFF0000u) | (u0 >> 16);
    H.y = (u3 & 0xFFFF0000u) | (u2 >> 16);
    float r0 = f0 - __uint_as_float(u0 & 0xFFFF0000u);
    float r1 = f1 - __uint_as_float(u1 & 0xFFFF0000u);
    float r2 = f2 - __uint_as_float(u2 & 0xFFFF0000u);
    float r3 = f3 - __uint_as_float(u3 & 0xFFFF0000u);
    L.x = (__float_as_uint(r0) >> 16) | (__float_as_uint(r1) & 0xFFFF0000u);
    L.y = (__float_as_uint(r2) >> 16) | (__float_as_uint(r3) & 0xFFFF0000u);
}

// -------- node GEMM, 64 rows x 64 cols per block, two L1-sized W passes --------
// X = (DEC ? decode(enc)+bprev : Xf); CA = X@WA[:,ch*64:+64] + biasA;
// if HASB: second pass CB = X@WB[:, same cols] (separate pass keeps the 32KB
// W slice L1-resident). DEC && ch==0 blocks also zero encZ rows (ping-pong).
template <int K, bool HASB, bool DEC>
__global__ __launch_bounds__(256) void k_gemm64(
    const float* __restrict__ Xf, const unsigned int* __restrict__ enc,
    unsigned int* __restrict__ encZ, const float* __restrict__ bprev,
    const float* __restrict__ WA, const float* __restrict__ WB,
    const float* __restrict__ biasA,
    float* __restrict__ CA, float* __restrict__ CB, int M)
{
    constexpr int LDX = K + 4;
    __shared__ float Xs[64 * LDX];
    const int t = threadIdx.x;
    const int row0 = (blockIdx.x >> 1) * 64;
    const int ch   = (blockIdx.x & 1) * 64;      // col half
    constexpr int F4R = K / 4;
    for (int i = t; i < 64 * F4R; i += 256) {
        int r = i / F4R, f = i % F4R;
        int gr = row0 + r;
        float4 v = make_float4(0.f, 0.f, 0.f, 0.f);
        if (gr < M) {
            if constexpr (DEC) {
                uint4 u = *(const uint4*)(enc + (size_t)gr * K + 4 * f);
                v.x = decenc(u.x) + bprev[4 * f + 0];
                v.y = decenc(u.y) + bprev[4 * f + 1];
                v.z = decenc(u.z) + bprev[4 * f + 2];
                v.w = decenc(u.w) + bprev[4 * f + 3];
                if (encZ && ch == 0) {
                    uint4 z = make_uint4(0u, 0u, 0u, 0u);
                    *(uint4*)(encZ + (size_t)gr * K + 4 * f) = z;
                }
            } else {
                v = *(const float4*)(Xf + (size_t)gr * K + 4 * f);
            }
        }
        *(float4*)(Xs + r * LDX + 4 * f) = v;
    }
    __syncthreads();

    const int rg = t >> 4, cg = t & 15;      // 4 rows x 4 cols per thread
    // ---- pass A ----
    {
        float accA[4][4];
#pragma unroll
        for (int i = 0; i < 4; ++i)
#pragma unroll
            for (int j = 0; j < 4; ++j) accA[i][j] = 0.f;
#pragma unroll 4
        for (int k = 0; k < K; ++k) {
            float4 wa = *(const float4*)(WA + k * 128 + ch + cg * 4);
            float xs[4];
#pragma unroll
            for (int i = 0; i < 4; ++i) xs[i] = Xs[(rg * 4 + i) * LDX + k];
#pragma unroll
            for (int i = 0; i < 4; ++i) {
                accA[i][0] += xs[i] * wa.x; accA[i][1] += xs[i] * wa.y;
                accA[i][2] += xs[i] * wa.z; accA[i][3] += xs[i] * wa.w;
            }
        }
        float4 b = *(const float4*)(biasA + ch + cg * 4);
#pragma unroll
        for (int i = 0; i < 4; ++i) {
            int r = row0 + rg * 4 + i;
            if (r < M) {
                *(float4*)(CA + (size_t)r * 128 + ch + cg * 4) =
                    make_float4(accA[i][0] + b.x, accA[i][1] + b.y,
                                accA[i][2] + b.z, accA[i][3] + b.w);
            }
        }
    }
    // ---- pass B ----
    if constexpr (HASB) {
        float accB[4][4];
#pragma unroll
        for (int i = 0; i < 4; ++i)
#pragma unroll
            for (int j = 0; j < 4; ++j) accB[i][j] = 0.f;
#pragma unroll 4
        for (int k = 0; k < K; ++k) {
            float4 wb = *(const float4*)(WB + k * 128 + ch + cg * 4);
            float xs[4];
#pragma unroll
            for (int i = 0; i < 4; ++i) xs[i] = Xs[(rg * 4 + i) * LDX + k];
#pragma unroll
            for (int i = 0; i < 4; ++i) {
                accB[i][0] += xs[i] * wb.x; accB[i][1] += xs[i] * wb.y;
                accB[i][2] += xs[i] * wb.z; accB[i][3] += xs[i] * wb.w;
            }
        }
#pragma unroll
        for (int i = 0; i < 4; ++i) {
            int r = row0 + rg * 4 + i;
            if (r < M) {
                *(float4*)(CB + (size_t)r * 128 + ch + cg * 4) =
                    make_float4(accB[i][0], accB[i][1], accB[i][2], accB[i][3]);
            }
        }
    }
}

// ---------------- EdgeConv v9: R8 structure + trunc-lo split ----------------
// Wave wv owns col-tile [wv*32,+32) x BOTH 32-edge slabs. Wave's FULL B
// (16 short8v = 64 VGPR) loaded from W2f before staging (latency hides under
// staging VALU); k-loop is pure ds_read+MFMA. Fragment-linear swizzled LDS.
__global__ __launch_bounds__(256, 4) void k_edge9(
    const float* __restrict__ A, const float* __restrict__ Bm,
    const int* __restrict__ esrc, const int* __restrict__ edst,
    const short* __restrict__ W2l, unsigned int* __restrict__ enc)
{
    __shared__ __align__(16) short Ts[2048 * 8];   // 32 KB, fragment-linear
    __shared__ int dsts[EB8];

    const int t = threadIdx.x;
    const int lane = t & 63;
    const int wv   = t >> 6;
    // bijective XCD-chunked block swizzle (m204 form)
    const int nwg = (int)gridDim.x;
    const int orig = (int)blockIdx.x;
    const int xcd = orig & 7, idx = orig >> 3;
    const int qq = nwg >> 3, rr = nwg & 7;
    const int bid = (xcd < rr ? xcd * (qq + 1) : rr * (qq + 1) + (xcd - rr) * qq) + idx;
    const int s0 = bid * EB8;

    // ---- issue the wave's full B-fragment set first ----
    const short* Wp = W2l + (size_t)wv * 1024 + (size_t)lane * 8;
    short8v bfh[8], bfl[8];
#pragma unroll
    for (int c = 0; c < 8; ++c) {
        bfh[c] = *(const short8v*)(Wp + (size_t)c * 4096);
        bfl[c] = *(const short8v*)(Wp + (size_t)c * 4096 + 512);
    }

    // ---- stage T hi/lo (4 threads per edge slot; quad = one 64B line per r) ----
    {
        const int row = t >> 2;          // edge slot within block
        const int q   = t & 3;
        const int slot = s0 + row;
        int dst = -1, src = 0;
        if (slot < NT) { dst = edst[slot]; src = esrc[slot]; }
        if (q == 0) dsts[row] = dst;
        const int sfrag = row >> 5;      // slab
        const int mrow  = row & 31;
        const int kh    = q >> 1;
        const int half  = q & 1;
        const int lbase = kh * 32 + mrow;

        if (dst >= 0) {
            const float* Ar = A  + (size_t)dst * HIDDEN + q * 4;
            const float* Br = Bm + (size_t)src * HIDDEN + q * 4;
#pragma unroll
            for (int r = 0; r < 8; ++r) {
                float4 av = *(const float4*)(Ar + r * 16);
                float4 bv = *(const float4*)(Br + r * 16);
                uint2 H, L;
                radd_split4(av, bv, H, L);
                const int c  = r;
                const int ih = ((sfrag)     * 8 + c) * 64 + lbase;   // p=0
                const int il = ((2 + sfrag) * 8 + c) * 64 + lbase;   // p=1
                *(uint2*)(&Ts[(size_t)(ih ^ c) * 8 + half * 4]) = H;
                *(uint2*)(&Ts[(size_t)(il ^ c) * 8 + half * 4]) = L;
            }
        } else {
            uint2 z = make_uint2(0u, 0u);
#pragma unroll
            for (int r = 0; r < 8; ++r) {
                const int c  = r;
                const int ih = ((sfrag)     * 8 + c) * 64 + lbase;
                const int il = ((2 + sfrag) * 8 + c) * 64 + lbase;
                *(uint2*)(&Ts[(size_t)(ih ^ c) * 8 + half * 4]) = z;
                *(uint2*)(&Ts[(size_t)(il ^ c) * 8 + half * 4]) = z;
            }
        }
    }
    __syncthreads();   // the only block barrier

    f32x16 acc0 = {0,0,0,0,0,0,0,0,0,0,0,0,0,0,0,0};   // slab 0 (rows 0-31)
    f32x16 acc1 = {0,0,0,0,0,0,0,0,0,0,0,0,0,0,0,0};   // slab 1 (rows 32-63)

#pragma unroll
    for (int c = 0; c < 8; ++c) {
        short8v ah0 = *(const short8v*)(&Ts[(size_t)(((0 * 8 + c) * 64 + lane) ^ c) * 8]);
        short8v ah1 = *(const short8v*)(&Ts[(size_t)(((1 * 8 + c) * 64 + lane) ^ c) * 8]);
        short8v al0 = *(const short8v*)(&Ts[(size_t)(((2 * 8 + c) * 64 + lane) ^ c) * 8]);
        short8v al1 = *(const short8v*)(&Ts[(size_t)(((3 * 8 + c) * 64 + lane) ^ c) * 8]);
        acc0 = __builtin_amdgcn_mfma_f32_32x32x16_bf16(ah0, bfh[c], acc0, 0, 0, 0);
        acc0 = __builtin_amdgcn_mfma_f32_32x32x16_bf16(al0, bfh[c], acc0, 0, 0, 0);
        acc0 = __builtin_amdgcn_mfma_f32_32x32x16_bf16(ah0, bfl[c], acc0, 0, 0, 0);
        acc1 = __builtin_amdgcn_mfma_f32_32x32x16_bf16(ah1, bfh[c], acc1, 0, 0, 0);
        acc1 = __builtin_amdgcn_mfma_f32_32x32x16_bf16(al1, bfh[c], acc1, 0, 0, 0);
        acc1 = __builtin_amdgcn_mfma_f32_32x32x16_bf16(ah1, bfl[c], acc1, 0, 0, 0);
    }

    // ---- aggregation ----
    const int m   = lane & 31;
    const int kh  = lane >> 5;
    const int col = wv * 32 + m;
    const int d_first = dsts[0];
    const int d_last  = dsts[EB8 - 1];
    if (d_first == d_last) {             // whole block one dst (sorted slots)
        if (d_first >= 0) {
            float mx = fmaxf(acc0[0], acc1[0]);
#pragma unroll
            for (int r = 1; r < 16; ++r)
                mx = fmaxf(mx, fmaxf(acc0[r], acc1[r]));
            atomicMax(&enc[(size_t)d_first * HIDDEN + col], encf(mx));
        }
    } else {
        {
            float run = -3.4e38f;
            int curd = dsts[4 * kh];
#pragma unroll
            for (int r = 0; r < 16; ++r) {
                const int er = (r & 3) + 8 * (r >> 2) + 4 * kh;
                int d = dsts[er];
                if (d != curd) {
                    if (curd >= 0)
                        atomicMax(&enc[(size_t)curd * HIDDEN + col], encf(run));
                    curd = d;
                    run = -3.4e38f;
                }
                run = fmaxf(run, acc0[r]);
            }
            if (curd >= 0)
                atomicMax(&enc[(size_t)curd * HIDDEN + col], encf(run));
        }
        {
            float run = -3.4e38f;
            int curd = dsts[32 + 4 * kh];
#pragma unroll
            for (int r = 0; r < 16; ++r) {
                const int er = 32 + (r & 3) + 8 * (r >> 2) + 4 * kh;
                int d = dsts[er];
                if (d != curd) {
                    if (curd >= 0)
                        atomicMax(&enc[(size_t)curd * HIDDEN + col], encf(run));
                    curd = d;
                    run = -3.4e38f;
                }
                run = fmaxf(run, acc1[r]);
            }
            if (curd >= 0)
                atomicMax(&enc[(size_t)curd * HIDDEN + col], encf(run));
        }
    }
}

// ---------------- launch ----------------
extern "C" void kernel_launch(void* const* d_in, const int* in_sizes, int n_in,
                              void* d_out, int out_size, void* d_ws, size_t ws_size,
                              hipStream_t stream)
{
    const float* x     = (const float*)d_in[0];
    const int*   ei    = (const int*)d_in[1];
    const float* W_emb = (const float*)d_in[2];
    const float* b_emb = (const float*)d_in[3];
    const float* W1    = (const float*)d_in[4];
    const float* b1    = (const float*)d_in[5];
    const float* W2    = (const float*)d_in[6];
    const float* b2    = (const float*)d_in[7];
    const float* W_fc  = (const float*)d_in[8];
    const float* b_fc  = (const float*)d_in[9];
    float* out = (float*)d_out;

    char* p = (char*)d_ws;
    auto alloc = [&](size_t bytes) {
        char* r = p;
        p += (bytes + 255) & ~(size_t)255;
        return r;
    };
    float* h    = (float*)alloc((size_t)N_NODES * HIDDEN * 4);
    float* Ab   = (float*)alloc((size_t)N_NODES * HIDDEN * 4);
    float* Bb   = (float*)alloc((size_t)N_NODES * HIDDEN * 4);
    unsigned int* enc0 = (unsigned int*)alloc((size_t)N_NODES * HIDDEN * 4);
    unsigned int* enc1 = (unsigned int*)alloc((size_t)N_NODES * HIDDEN * 4);
    float* Wa   = (float*)alloc((size_t)NUM_LAYERS * 16384 * 4);
    float* Wb   = (float*)alloc((size_t)NUM_LAYERS * 16384 * 4);
    short* W2f  = (short*)alloc((size_t)NUM_LAYERS * 32768 * 2);
    int* cursor = (int*)alloc(N_NODES * 4);
    int* cnt    = (int*)alloc(N_NODES * 4);
    int* esrc   = (int*)alloc((size_t)NT * 4);
    int* edst   = (int*)alloc((size_t)NT * 4);
    int* srcN   = (int*)alloc((size_t)N_EDGES * 4);
    int* dstN   = (int*)alloc((size_t)N_EDGES * 4);
    int* flag   = (int*)alloc(4);

    unsigned int* encs[2] = {enc0, enc1};

    const int EBLK = (N_EDGES + 255) / 256;
    const int GB   = 2 * ((N_NODES + 63) / 64);   // 314 (row-tiles x col-halves)
    const int EG   = (NT + EB8 - 1) / EB8;        // 10157

    k_init<<<(N_NODES * HIDDEN + 255) / 256, 256, 0, stream>>>(ei, flag, cnt, enc0);
    k_norm_count<<<EBLK, 256, 0, stream>>>(ei, flag, srcN, dstN, cnt);
    k_scan<<<1, 256, 0, stream>>>(cnt, cursor);
    k_scatter_all<<<(NT + 255) / 256, 256, 0, stream>>>(srcN, dstN, cursor, esrc, edst);
    k_prepww<<<(NUM_LAYERS * 16384 + 255) / 256, 256, 0, stream>>>(W1, W2, Wa, Wb, W2f);

    // embedding: h = x @ W_emb + b_emb
    k_gemm64<NODE_DIM, false, false><<<GB, 256, 0, stream>>>(
        x, nullptr, nullptr, nullptr, W_emb, nullptr, b_emb, h, nullptr, N_NODES);

    for (int l = 0; l < NUM_LAYERS; ++l) {
        if (l == 0) {
            // enc0 zeroed by k_init; edge 0 writes enc0
            k_gemm64<HIDDEN, true, false><<<GB, 256, 0, stream>>>(
                h, nullptr, nullptr, nullptr, Wa, Wb, b1, Ab, Bb, N_NODES);
        } else {
            // decode enc[(l-1)&1], zero enc[l&1] (ping-pong, idempotent writes)
            k_gemm64<HIDDEN, true, true><<<GB, 256, 0, stream>>>(
                nullptr, encs[(l - 1) & 1], encs[l & 1], b2 + (l - 1) * 128,
                Wa + l * 16384, Wb + l * 16384, b1 + l * 128, Ab, Bb, N_NODES);
        }
        k_edge9<<<EG, 256, 0, stream>>>(Ab, Bb, esrc, edst,
                                        W2f + (size_t)l * 32768, encs[l & 1]);
    }
    // final fc decodes enc[(L-1)&1] + b2[3]
    k_gemm64<HIDDEN, false, true><<<GB, 256, 0, stream>>>(
        nullptr, encs[(NUM_LAYERS - 1) & 1], nullptr, b2 + 3 * 128,
        W_fc, nullptr, b_fc, out, nullptr, N_NODES);
}